// Round 1
// baseline (22728.102 us; speedup 1.0000x reference)
//
#include <hip/hip_runtime.h>
#include <hip/hip_fp16.h>

// LSTM (2-layer bidirectional, B=64 T=1024 I=H=256) for MI355X.
// Structure:
//   1. pack x -> f16 [t*B+b][I] (GEMM A layout)
//   2. pack all weights -> f16 MFMA B-fragment-linear layout; bias sums fp32
//   3. gemm_xg (f16 MFMA, fp32 acc): xg[d][t*B+b][4H] = x @ W_ih^T + b  (f16 store)
//   4. lstm_rec: 8 persistent WGs (dir x 16-batch chunk), h/c resident,
//      per step: MFMA [16,256]x[256,1024] from LDS-h x L2-resident packed W_hh,
//      gates in fp32 (exp2-based sigmoid/tanh), h -> LDS + output stream.
//   layer 1 repeats 3-4 with K=512 (o1 = [fwd h, bwd h] f16).
// d_out = o2 [B,T,512] fp32 ++ h_n [4,B,H] ++ c_n [4,B,H].

#define BQ 64
#define TT 1024
#define II 256
#define M0 (BQ * TT)  // 65536

typedef _Float16 half8 __attribute__((ext_vector_type(8)));
typedef float floatx4 __attribute__((ext_vector_type(4)));

__device__ __forceinline__ float fsig(float x) {
  float e = __builtin_amdgcn_exp2f(-1.44269504089f * x);
  return __builtin_amdgcn_rcpf(1.0f + e);
}
__device__ __forceinline__ float ftanh(float x) {
  float ax = __builtin_fabsf(x);
  float e = __builtin_amdgcn_exp2f(-2.88539008178f * ax);
  float r = (1.0f - e) * __builtin_amdgcn_rcpf(1.0f + e);
  return __builtin_copysignf(r, x);
}
__device__ __forceinline__ half8 cvt8(float4 a, float4 b) {
  half8 h;
  h[0] = (_Float16)a.x; h[1] = (_Float16)a.y; h[2] = (_Float16)a.z; h[3] = (_Float16)a.w;
  h[4] = (_Float16)b.x; h[5] = (_Float16)b.y; h[6] = (_Float16)b.z; h[7] = (_Float16)b.w;
  return h;
}

// x [B,T,I] fp32 -> xT [(t*B+b), I] f16
__global__ __launch_bounds__(256) void pack_xT(const float* __restrict__ x,
                                               _Float16* __restrict__ xT) {
  int gid = blockIdx.x * 256 + threadIdx.x;  // one thread per 8 elems
  int chunk = gid & 31;                      // 32 chunks of 8 per row
  int row = gid >> 5;                        // row = t*64 + b
  int t = row >> 6, b = row & 63;
  const float* src = x + ((size_t)b * TT + t) * II + chunk * 8;
  float4 v0 = *(const float4*)src;
  float4 v1 = *(const float4*)(src + 4);
  *(half8*)(xT + (size_t)row * II + chunk * 8) = cvt8(v0, v1);
}

// W fp32 [D][1024][K] -> f16 B-fragment layout [d][tile][ks][lane][8]
// fragment: n = tile*16 + (lane&15), k = ks*32 + (lane>>4)*8 + j
__global__ __launch_bounds__(256) void pack_B(const float* __restrict__ W,
                                              _Float16* __restrict__ dst, int K,
                                              int total) {
  int gid = blockIdx.x * 256 + threadIdx.x;
  if (gid >= total) return;
  int per = 64 * (K / 32) * 64;  // threads per dir
  int d = gid / per;
  int i = gid - d * per;
  int lane = i & 63;
  int i2 = i >> 6;  // tile*(K/32) + ks
  int n = (i2 / (K / 32)) * 16 + (lane & 15);
  int k = (i2 % (K / 32)) * 32 + (lane >> 4) * 8;
  const float* s = W + ((size_t)d * 1024 + n) * K + k;
  float4 v0 = *(const float4*)s;
  float4 v1 = *(const float4*)(s + 4);
  *(half8*)(dst + (size_t)gid * 8) = cvt8(v0, v1);
}

__global__ __launch_bounds__(256) void add_bias(const float* __restrict__ a,
                                                const float* __restrict__ b,
                                                float* __restrict__ o, int n) {
  int i = blockIdx.x * 256 + threadIdx.x;
  if (i < n) o[i] = a[i] + b[i];
}

// out[d][m][n] = sum_k A[m][k]*W[d][n][k] + bias[d][n], f16 store. M=65536, N=1024.
// 128x128 tile, 4 waves (2x2), 4x4 16x16x32 f16 MFMA per wave.
template <int K>
__global__ __launch_bounds__(256) void gemm_xg(const _Float16* __restrict__ A,
                                               const _Float16* __restrict__ Bp,
                                               const float* __restrict__ bias,
                                               _Float16* __restrict__ out) {
  const int d = blockIdx.z;
  const int n0 = blockIdx.x * 128;
  const int m0 = blockIdx.y * 128;
  const int tid = threadIdx.x;
  const int lane = tid & 63, wave = tid >> 6;
  const int wr = wave >> 1, wc = wave & 1;
  const int cl = lane & 15, lh = lane >> 4;
  __shared__ _Float16 As[128][48];  // pad 32->48 (96B row stride, 16B aligned)
  const _Float16* Bb = Bp + (size_t)d * (1024 * K);
  floatx4 acc[4][4];
#pragma unroll
  for (int i = 0; i < 4; i++)
#pragma unroll
    for (int j = 0; j < 4; j++) acc[i][j] = (floatx4){0.f, 0.f, 0.f, 0.f};

  for (int ks = 0; ks < K / 32; ++ks) {
#pragma unroll
    for (int it = 0; it < 2; ++it) {  // stage A tile 128x32 f16
      int row = it * 64 + (tid >> 2);
      int col = (tid & 3) * 8;
      *(half8*)(&As[row][col]) =
          *(const half8*)(A + (size_t)(m0 + row) * K + ks * 32 + col);
    }
    __syncthreads();
    half8 a[4], b[4];
#pragma unroll
    for (int rt = 0; rt < 4; rt++)
      a[rt] = *(const half8*)(&As[wr * 64 + rt * 16 + cl][lh * 8]);
#pragma unroll
    for (int ct = 0; ct < 4; ct++) {
      int tile = (n0 >> 4) + wc * 4 + ct;
      b[ct] = *(const half8*)(Bb + ((size_t)(tile * (K / 32) + ks) * 64 + lane) * 8);
    }
#pragma unroll
    for (int rt = 0; rt < 4; rt++)
#pragma unroll
      for (int ct = 0; ct < 4; ct++)
        acc[rt][ct] = __builtin_amdgcn_mfma_f32_16x16x32_f16(a[rt], b[ct], acc[rt][ct], 0, 0, 0);
    __syncthreads();
  }
#pragma unroll
  for (int ct = 0; ct < 4; ct++) {
    int n = n0 + wc * 64 + ct * 16 + cl;
    float bv = bias[d * 1024 + n];
#pragma unroll
    for (int rt = 0; rt < 4; rt++) {
      int mb = m0 + wr * 64 + rt * 16 + lh * 4;
#pragma unroll
      for (int r = 0; r < 4; r++)
        out[(size_t)d * ((size_t)M0 * 1024) + (size_t)(mb + r) * 1024 + n] =
            (_Float16)(acc[rt][ct][r] + bv);
    }
  }
}

// Persistent recurrence. 8 WGs: dir = wg>>2, batch chunk b0 = (wg&3)*16.
// 512 threads = 8 waves; wave w owns N-tiles {w + 8q}, so (i,f,g,o) of a given
// hidden index j stay in one lane (q, q+2, q+4, q+6). c in regs, h via LDS.
template <int LAYER>
__global__ __launch_bounds__(512) void lstm_rec(const _Float16* __restrict__ xg,
                                                const _Float16* __restrict__ Whp,
                                                _Float16* __restrict__ o1,
                                                float* __restrict__ out) {
  const int wg = blockIdx.x;
  const int dir = wg >> 2;
  const int b0 = (wg & 3) << 4;
  const int tid = threadIdx.x;
  const int lane = tid & 63, wave = tid >> 6;
  const int cl = lane & 15, lh = lane >> 4;
  __shared__ _Float16 hl[16][264];  // h [16 batch][256], pad row to 528B (2-way free)
  for (int i = tid; i < 16 * 264; i += 512) (&hl[0][0])[i] = (_Float16)0.f;
  float c[8];
#pragma unroll
  for (int i = 0; i < 8; i++) c[i] = 0.f;
  const _Float16* Wb = Whp + (size_t)dir * (1024 * 256);
  const size_t o2elems = (size_t)BQ * TT * 512;
  __syncthreads();

  for (int t = 0; t < TT; ++t) {
    const int tt = dir ? (TT - 1 - t) : t;
    const _Float16* xgrow = xg + ((size_t)dir * M0 + (size_t)tt * BQ + b0) * 1024;
    floatx4 acc[8];
    float xf[8][4];
    // issue xg loads first; consumed after K-loop so HBM latency hides under MFMA
#pragma unroll
    for (int q = 0; q < 8; q++) {
      int n = (wave + 8 * q) * 16 + cl;
#pragma unroll
      for (int r = 0; r < 4; r++)
        xf[q][r] = (float)xgrow[(size_t)(lh * 4 + r) * 1024 + n];
      acc[q] = (floatx4){0.f, 0.f, 0.f, 0.f};
    }
#pragma unroll
    for (int ks = 0; ks < 8; ks++) {
      half8 a = *(const half8*)(&hl[cl][ks * 32 + lh * 8]);
#pragma unroll
      for (int q = 0; q < 8; q++) {
        half8 b = *(const half8*)(Wb + ((size_t)((wave + 8 * q) * 8 + ks) * 64 + lane) * 8);
        acc[q] = __builtin_amdgcn_mfma_f32_16x16x32_f16(a, b, acc[q], 0, 0, 0);
      }
    }
    __syncthreads();  // all hl reads done before overwrite
#pragma unroll
    for (int jq = 0; jq < 2; jq++) {
#pragma unroll
      for (int r = 0; r < 4; r++) {
        int ci = jq * 4 + r;
        float gi = acc[jq][r] + xf[jq][r];
        float gf = acc[jq + 2][r] + xf[jq + 2][r];
        float gg = acc[jq + 4][r] + xf[jq + 4][r];
        float go = acc[jq + 6][r] + xf[jq + 6][r];
        float cc = fsig(gf) * c[ci] + fsig(gi) * ftanh(gg);
        c[ci] = cc;
        float h = fsig(go) * ftanh(cc);
        int bl = lh * 4 + r;                 // batch-local row (D-layout row)
        int j = (wave + 8 * jq) * 16 + cl;   // hidden index 0..255
        hl[bl][j] = (_Float16)h;
        if (LAYER == 0) {
          o1[((size_t)tt * BQ + b0 + bl) * 512 + dir * 256 + j] = (_Float16)h;
        } else {
          out[((size_t)(b0 + bl) * TT + tt) * 512 + dir * 256 + j] = h;
        }
        if (t == TT - 1) {  // final states -> h_n / c_n
          int row = LAYER * 2 + dir;
          out[o2elems + ((size_t)row * BQ + b0 + bl) * 256 + j] = h;
          out[o2elems + (size_t)4 * BQ * 256 + ((size_t)row * BQ + b0 + bl) * 256 + j] = cc;
        }
      }
    }
    __syncthreads();  // new h visible before next step's reads
  }
}

extern "C" void kernel_launch(void* const* d_in, const int* in_sizes, int n_in,
                              void* d_out, int out_size, void* d_ws, size_t ws_size,
                              hipStream_t stream) {
  (void)in_sizes; (void)n_in; (void)out_size; (void)ws_size;
  const float* x = (const float*)d_in[0];
  // d_in[1] = hidden_state, ignored by the module
  const float* wih0 = (const float*)d_in[2];
  const float* whh0 = (const float*)d_in[3];
  const float* bih0 = (const float*)d_in[4];
  const float* bhh0 = (const float*)d_in[5];
  const float* wih1 = (const float*)d_in[6];
  const float* whh1 = (const float*)d_in[7];
  const float* bih1 = (const float*)d_in[8];
  const float* bhh1 = (const float*)d_in[9];
  float* out = (float*)d_out;

  char* p = (char*)d_ws;  // ~357 MB total
  _Float16* xT = (_Float16*)p;    p += (size_t)M0 * II * 2;        // 32 MB
  _Float16* o1 = (_Float16*)p;    p += (size_t)M0 * 512 * 2;       // 64 MB
  _Float16* xgb = (_Float16*)p;   p += (size_t)2 * M0 * 1024 * 2;  // 256 MB (reused by both layers)
  _Float16* pwih0 = (_Float16*)p; p += (size_t)2 * 1024 * 256 * 2;
  _Float16* pwhh0 = (_Float16*)p; p += (size_t)2 * 1024 * 256 * 2;
  _Float16* pwih1 = (_Float16*)p; p += (size_t)2 * 1024 * 512 * 2;
  _Float16* pwhh1 = (_Float16*)p; p += (size_t)2 * 1024 * 256 * 2;
  float* bias0 = (float*)p;       p += 2 * 1024 * 4;
  float* bias1 = (float*)p;       p += 2 * 1024 * 4;

  hipLaunchKernelGGL(pack_xT, dim3(8192), dim3(256), 0, stream, x, xT);
  hipLaunchKernelGGL(pack_B, dim3(256), dim3(256), 0, stream, wih0, pwih0, 256, 2 * 1024 * 256 / 8);
  hipLaunchKernelGGL(pack_B, dim3(256), dim3(256), 0, stream, whh0, pwhh0, 256, 2 * 1024 * 256 / 8);
  hipLaunchKernelGGL(pack_B, dim3(512), dim3(256), 0, stream, wih1, pwih1, 512, 2 * 1024 * 512 / 8);
  hipLaunchKernelGGL(pack_B, dim3(256), dim3(256), 0, stream, whh1, pwhh1, 256, 2 * 1024 * 256 / 8);
  hipLaunchKernelGGL(add_bias, dim3(8), dim3(256), 0, stream, bih0, bhh0, bias0, 2048);
  hipLaunchKernelGGL(add_bias, dim3(8), dim3(256), 0, stream, bih1, bhh1, bias1, 2048);

  hipLaunchKernelGGL((gemm_xg<256>), dim3(8, 512, 2), dim3(256), 0, stream, xT, pwih0, bias0, xgb);
  hipLaunchKernelGGL((lstm_rec<0>), dim3(8), dim3(512), 0, stream, xgb, pwhh0, o1, out);
  hipLaunchKernelGGL((gemm_xg<512>), dim3(8, 512, 2), dim3(256), 0, stream, o1, pwih1, bias1, xgb);
  hipLaunchKernelGGL((lstm_rec<1>), dim3(8), dim3(512), 0, stream, xgb, pwhh1, (_Float16*)nullptr, out);
}

// Round 2
// 17478.481 us; speedup vs baseline: 1.3003x; 1.3003x over previous
//
#include <hip/hip_runtime.h>
#include <hip/hip_fp16.h>

// LSTM (2-layer bidirectional, B=64 T=1024 I=H=256) for MI355X.
// R2: register-resident W_hh. Per direction, 4 WGs each hold a 128KB W_hh
// slice (4 gates x 64 hidden rows) in VGPRs (32 B-frags = 128 VGPR/thread).
// Per step: h read from a global exchange buffer (IC-coherent), MFMA
// [64,256]@[256,256], gates, h-slice written back + device-scope atomic
// counter barrier among the 4 WGs of the direction. No LDS, no per-step
// weight traffic.
// d_out = o2 [B,T,512] fp32 ++ h_n [4,B,H] ++ c_n [4,B,H].

#define BQ 64
#define TT 1024
#define II 256
#define M0 (BQ * TT)  // 65536
#define G4 4          // WGs per direction (hidden slices)

typedef _Float16 half8 __attribute__((ext_vector_type(8)));
typedef float floatx4 __attribute__((ext_vector_type(4)));

__device__ __forceinline__ float fsig(float x) {
  float e = __builtin_amdgcn_exp2f(-1.44269504089f * x);
  return __builtin_amdgcn_rcpf(1.0f + e);
}
__device__ __forceinline__ float ftanh(float x) {
  float ax = __builtin_fabsf(x);
  float e = __builtin_amdgcn_exp2f(-2.88539008178f * ax);
  float r = (1.0f - e) * __builtin_amdgcn_rcpf(1.0f + e);
  return __builtin_copysignf(r, x);
}
__device__ __forceinline__ half8 cvt8(float4 a, float4 b) {
  half8 h;
  h[0] = (_Float16)a.x; h[1] = (_Float16)a.y; h[2] = (_Float16)a.z; h[3] = (_Float16)a.w;
  h[4] = (_Float16)b.x; h[5] = (_Float16)b.y; h[6] = (_Float16)b.z; h[7] = (_Float16)b.w;
  return h;
}

// x [B,T,I] fp32 -> xT [(t*B+b), I] f16
__global__ __launch_bounds__(256) void pack_xT(const float* __restrict__ x,
                                               _Float16* __restrict__ xT) {
  int gid = blockIdx.x * 256 + threadIdx.x;  // one thread per 8 elems
  int chunk = gid & 31;                      // 32 chunks of 8 per row
  int row = gid >> 5;                        // row = t*64 + b
  int t = row >> 6, b = row & 63;
  const float* src = x + ((size_t)b * TT + t) * II + chunk * 8;
  float4 v0 = *(const float4*)src;
  float4 v1 = *(const float4*)(src + 4);
  *(half8*)(xT + (size_t)row * II + chunk * 8) = cvt8(v0, v1);
}

// W fp32 [D][1024][K] -> f16 B-fragment layout [d][tile][ks][lane][8]
// fragment: n = tile*16 + (lane&15), k = ks*32 + (lane>>4)*8 + j
__global__ __launch_bounds__(256) void pack_B(const float* __restrict__ W,
                                              _Float16* __restrict__ dst, int K,
                                              int total) {
  int gid = blockIdx.x * 256 + threadIdx.x;
  if (gid >= total) return;
  int per = 64 * (K / 32) * 64;  // threads per dir
  int d = gid / per;
  int i = gid - d * per;
  int lane = i & 63;
  int i2 = i >> 6;  // tile*(K/32) + ks
  int n = (i2 / (K / 32)) * 16 + (lane & 15);
  int k = (i2 % (K / 32)) * 32 + (lane >> 4) * 8;
  const float* s = W + ((size_t)d * 1024 + n) * K + k;
  float4 v0 = *(const float4*)s;
  float4 v1 = *(const float4*)(s + 4);
  *(half8*)(dst + (size_t)gid * 8) = cvt8(v0, v1);
}

__global__ __launch_bounds__(256) void add_bias(const float* __restrict__ a,
                                                const float* __restrict__ b,
                                                float* __restrict__ o, int n) {
  int i = blockIdx.x * 256 + threadIdx.x;
  if (i < n) o[i] = a[i] + b[i];
}

// out[d][m][n] = sum_k A[m][k]*W[d][n][k] + bias[d][n], f16 store. M=65536, N=1024.
// 128x128 tile, 4 waves (2x2), 4x4 16x16x32 f16 MFMA per wave.
template <int K>
__global__ __launch_bounds__(256) void gemm_xg(const _Float16* __restrict__ A,
                                               const _Float16* __restrict__ Bp,
                                               const float* __restrict__ bias,
                                               _Float16* __restrict__ out) {
  const int d = blockIdx.z;
  const int n0 = blockIdx.x * 128;
  const int m0 = blockIdx.y * 128;
  const int tid = threadIdx.x;
  const int lane = tid & 63, wave = tid >> 6;
  const int wr = wave >> 1, wc = wave & 1;
  const int cl = lane & 15, lh = lane >> 4;
  __shared__ _Float16 As[128][48];  // pad 32->48
  const _Float16* Bb = Bp + (size_t)d * (1024 * K);
  floatx4 acc[4][4];
#pragma unroll
  for (int i = 0; i < 4; i++)
#pragma unroll
    for (int j = 0; j < 4; j++) acc[i][j] = (floatx4){0.f, 0.f, 0.f, 0.f};

  for (int ks = 0; ks < K / 32; ++ks) {
#pragma unroll
    for (int it = 0; it < 2; ++it) {  // stage A tile 128x32 f16
      int row = it * 64 + (tid >> 2);
      int col = (tid & 3) * 8;
      *(half8*)(&As[row][col]) =
          *(const half8*)(A + (size_t)(m0 + row) * K + ks * 32 + col);
    }
    __syncthreads();
    half8 a[4], b[4];
#pragma unroll
    for (int rt = 0; rt < 4; rt++)
      a[rt] = *(const half8*)(&As[wr * 64 + rt * 16 + cl][lh * 8]);
#pragma unroll
    for (int ct = 0; ct < 4; ct++) {
      int tile = (n0 >> 4) + wc * 4 + ct;
      b[ct] = *(const half8*)(Bb + ((size_t)(tile * (K / 32) + ks) * 64 + lane) * 8);
    }
#pragma unroll
    for (int rt = 0; rt < 4; rt++)
#pragma unroll
      for (int ct = 0; ct < 4; ct++)
        acc[rt][ct] = __builtin_amdgcn_mfma_f32_16x16x32_f16(a[rt], b[ct], acc[rt][ct], 0, 0, 0);
    __syncthreads();
  }
#pragma unroll
  for (int ct = 0; ct < 4; ct++) {
    int n = n0 + wc * 64 + ct * 16 + cl;
    float bv = bias[d * 1024 + n];
#pragma unroll
    for (int rt = 0; rt < 4; rt++) {
      int mb = m0 + wr * 64 + rt * 16 + lh * 4;
#pragma unroll
      for (int r = 0; r < 4; r++)
        out[(size_t)d * ((size_t)M0 * 1024) + (size_t)(mb + r) * 1024 + n] =
            (_Float16)(acc[rt][ct][r] + bv);
    }
  }
}

// Persistent recurrence, register-resident weights.
// 8 WGs: dir = wg>>2, hidden-slice s = wg&3 (64 hidden each).
// 8 waves as 2M x 4N: wr = wave>>2 (batch half, 2 M-tiles), wc = wave&3
// (16-hidden column within the slice). Lane holds i,f,g,o for ONE hidden
// index j across its 4 gate acc-tiles. c in regs. h exchanged via global
// buffer + device-scope atomic counter barrier among the 4 WGs of a dir.
template <int LAYER>
__global__ __launch_bounds__(512, 2) void lstm_rec(
    const _Float16* __restrict__ xg, const _Float16* __restrict__ Whp,
    _Float16* __restrict__ o1, float* __restrict__ out,
    _Float16* __restrict__ hx, unsigned* __restrict__ ctr) {
  const int wg = blockIdx.x;
  const int dir = wg >> 2, s = wg & 3;
  const int tid = threadIdx.x;
  const int lane = tid & 63, wave = tid >> 6;
  const int cl = lane & 15, lh = lane >> 4;
  const int wr = wave >> 2, wc = wave & 3;
  const int j = s * 64 + wc * 16 + cl;  // this lane's hidden index
  const int pair = LAYER * 2 + dir;
  unsigned* myctr = ctr + pair;
  _Float16* buf0 = hx + (size_t)(pair * 2 + 0) * (64 * 256);
  _Float16* buf1 = hx + (size_t)(pair * 2 + 1) * (64 * 256);
  const size_t o2elems = (size_t)BQ * TT * 512;

  // Load W fragments once: w[g][ks], tile = g*16 + s*4 + wc. 128 VGPRs.
  const _Float16* Wb = Whp + (size_t)dir * (1024 * 256);
  half8 w[4][8];
#pragma unroll
  for (int g = 0; g < 4; g++) {
    const int tile = g * 16 + s * 4 + wc;
#pragma unroll
    for (int ks = 0; ks < 8; ks++)
      w[g][ks] = *(const half8*)(Wb + ((size_t)(tile * 8 + ks) * 64 + lane) * 8);
  }
  float c[2][4];
#pragma unroll
  for (int mi = 0; mi < 2; mi++)
#pragma unroll
    for (int r = 0; r < 4; r++) c[mi][r] = 0.f;

  for (int t = 0; t < TT; ++t) {
    const int tt = dir ? (TT - 1 - t) : t;
    const _Float16* xgrow = xg + ((size_t)dir * M0 + (size_t)tt * BQ) * 1024;
    // xg prefetch (independent of the barrier; hides under poll+skew)
    float xf[2][4][4];
#pragma unroll
    for (int mi = 0; mi < 2; mi++)
#pragma unroll
      for (int g = 0; g < 4; g++)
#pragma unroll
        for (int r = 0; r < 4; r++)
          xf[mi][g][r] =
              (float)xgrow[(size_t)((wr * 2 + mi) * 16 + lh * 4 + r) * 1024 + g * 256 + j];

    // Wait for h_t: all 4 WGs of this dir committed step t-1 (also proves
    // everyone finished reading buf[(t+1)&1], so writing it below is safe).
    if (tid == 0) {
      const unsigned target = (unsigned)(G4 * t);
      while (__hip_atomic_load(myctr, __ATOMIC_RELAXED, __HIP_MEMORY_SCOPE_AGENT) <
             target) {
        __builtin_amdgcn_s_sleep(1);
      }
      __threadfence();  // acquire: inv L1/L2 so h reads see remote writes
    }
    __syncthreads();

    const _Float16* hr = (t & 1) ? buf1 : buf0;
    floatx4 acc[2][4];
#pragma unroll
    for (int mi = 0; mi < 2; mi++)
#pragma unroll
      for (int g = 0; g < 4; g++) acc[mi][g] = (floatx4){0.f, 0.f, 0.f, 0.f};
#pragma unroll
    for (int ks = 0; ks < 8; ks++) {
      half8 a0 = *(const half8*)(hr + (size_t)((wr * 2 + 0) * 16 + cl) * 256 + ks * 32 + lh * 8);
      half8 a1 = *(const half8*)(hr + (size_t)((wr * 2 + 1) * 16 + cl) * 256 + ks * 32 + lh * 8);
#pragma unroll
      for (int g = 0; g < 4; g++) {
        acc[0][g] = __builtin_amdgcn_mfma_f32_16x16x32_f16(a0, w[g][ks], acc[0][g], 0, 0, 0);
        acc[1][g] = __builtin_amdgcn_mfma_f32_16x16x32_f16(a1, w[g][ks], acc[1][g], 0, 0, 0);
      }
    }

    _Float16* hw = (t & 1) ? buf0 : buf1;
#pragma unroll
    for (int mi = 0; mi < 2; mi++)
#pragma unroll
      for (int r = 0; r < 4; r++) {
        float gi = acc[mi][0][r] + xf[mi][0][r];
        float gf = acc[mi][1][r] + xf[mi][1][r];
        float gg = acc[mi][2][r] + xf[mi][2][r];
        float go = acc[mi][3][r] + xf[mi][3][r];
        float cc = fsig(gf) * c[mi][r] + fsig(gi) * ftanh(gg);
        c[mi][r] = cc;
        float h = fsig(go) * ftanh(cc);
        const int b = (wr * 2 + mi) * 16 + lh * 4 + r;
        hw[(size_t)b * 256 + j] = (_Float16)h;
        if (LAYER == 0) {
          o1[((size_t)tt * BQ + b) * 512 + dir * 256 + j] = (_Float16)h;
        } else {
          out[((size_t)b * TT + tt) * 512 + dir * 256 + j] = h;
        }
        if (t == TT - 1) {
          const int row = LAYER * 2 + dir;
          out[o2elems + ((size_t)row * BQ + b) * 256 + j] = h;
          out[o2elems + (size_t)4 * BQ * 256 + ((size_t)row * BQ + b) * 256 + j] = cc;
        }
      }

    __syncthreads();  // barrier drains all waves' h stores (vmcnt 0) into L2
    if (tid == 0)     // release: wbl2 flushes L2 -> IC, then signal
      __hip_atomic_fetch_add(myctr, 1u, __ATOMIC_RELEASE, __HIP_MEMORY_SCOPE_AGENT);
  }
}

extern "C" void kernel_launch(void* const* d_in, const int* in_sizes, int n_in,
                              void* d_out, int out_size, void* d_ws, size_t ws_size,
                              hipStream_t stream) {
  (void)in_sizes; (void)n_in; (void)out_size; (void)ws_size;
  const float* x = (const float*)d_in[0];
  // d_in[1] = hidden_state, ignored by the module
  const float* wih0 = (const float*)d_in[2];
  const float* whh0 = (const float*)d_in[3];
  const float* bih0 = (const float*)d_in[4];
  const float* bhh0 = (const float*)d_in[5];
  const float* wih1 = (const float*)d_in[6];
  const float* whh1 = (const float*)d_in[7];
  const float* bih1 = (const float*)d_in[8];
  const float* bhh1 = (const float*)d_in[9];
  float* out = (float*)d_out;

  char* p = (char*)d_ws;
  unsigned* ctr = (unsigned*)p;   p += 256;                        // 4 counters
  _Float16* hx = (_Float16*)p;    p += (size_t)4 * 2 * 64 * 256 * 2;  // 256 KB exchange
  _Float16* xT = (_Float16*)p;    p += (size_t)M0 * II * 2;        // 32 MB
  _Float16* o1 = (_Float16*)p;    p += (size_t)M0 * 512 * 2;       // 64 MB
  _Float16* xgb = (_Float16*)p;   p += (size_t)2 * M0 * 1024 * 2;  // 256 MB
  _Float16* pwih0 = (_Float16*)p; p += (size_t)2 * 1024 * 256 * 2;
  _Float16* pwhh0 = (_Float16*)p; p += (size_t)2 * 1024 * 256 * 2;
  _Float16* pwih1 = (_Float16*)p; p += (size_t)2 * 1024 * 512 * 2;
  _Float16* pwhh1 = (_Float16*)p; p += (size_t)2 * 1024 * 256 * 2;
  float* bias0 = (float*)p;       p += 2 * 1024 * 4;
  float* bias1 = (float*)p;       p += 2 * 1024 * 4;

  // zero counters + h exchange buffers (re-poisoned 0xAA before every replay)
  hipMemsetAsync(d_ws, 0, 256 + (size_t)4 * 2 * 64 * 256 * 2, stream);

  hipLaunchKernelGGL(pack_xT, dim3(8192), dim3(256), 0, stream, x, xT);
  hipLaunchKernelGGL(pack_B, dim3(256), dim3(256), 0, stream, wih0, pwih0, 256, 2 * 1024 * 256 / 8);
  hipLaunchKernelGGL(pack_B, dim3(256), dim3(256), 0, stream, whh0, pwhh0, 256, 2 * 1024 * 256 / 8);
  hipLaunchKernelGGL(pack_B, dim3(512), dim3(256), 0, stream, wih1, pwih1, 512, 2 * 1024 * 512 / 8);
  hipLaunchKernelGGL(pack_B, dim3(256), dim3(256), 0, stream, whh1, pwhh1, 256, 2 * 1024 * 256 / 8);
  hipLaunchKernelGGL(add_bias, dim3(8), dim3(256), 0, stream, bih0, bhh0, bias0, 2048);
  hipLaunchKernelGGL(add_bias, dim3(8), dim3(256), 0, stream, bih1, bhh1, bias1, 2048);

  hipLaunchKernelGGL((gemm_xg<256>), dim3(8, 512, 2), dim3(256), 0, stream, xT, pwih0, bias0, xgb);
  hipLaunchKernelGGL((lstm_rec<0>), dim3(8), dim3(512), 0, stream, xgb, pwhh0, o1, out, hx, ctr);
  hipLaunchKernelGGL((gemm_xg<512>), dim3(8, 512, 2), dim3(256), 0, stream, o1, pwih1, bias1, xgb);
  hipLaunchKernelGGL((lstm_rec<1>), dim3(8), dim3(512), 0, stream, xgb, pwhh1, (_Float16*)nullptr, out, hx, ctr);
}